// Round 7
// baseline (120.579 us; speedup 1.0000x reference)
//
#include <hip/hip_runtime.h>
#include <hip/hip_bf16.h>

#define EPS 1e-5f

// dims: feat (2,128,128,128) f32 NCHW, guide (2,3,256,256) f32 NCHW,
// out (2,128,256,256) f32 NCHW. E=32, K=3, k2=9. H2=W2=256.
// x1,x2 bf16 NHWC (2,256,256,32) + stats scratch in d_out; fs bf16 NHWC,
// kern48 f32 [lowres px][4 subpx][12], packed weights in d_ws.

typedef unsigned short ushort_t;
typedef __attribute__((ext_vector_type(8))) short short8v;   // 8 bf16 = 4 VGPR
typedef __attribute__((ext_vector_type(4))) float f32x4;

__device__ __forceinline__ int swz(int b) { return b ^ (((b >> 7) & 7) << 4); }
__device__ __forceinline__ float bf2f(ushort_t u) {
    unsigned int t = ((unsigned int)u) << 16;
    return __builtin_bit_cast(float, t);
}
__device__ __forceinline__ ushort_t f2bf(float f) {   // RNE via HW cvt
    __hip_bfloat16 h = (__hip_bfloat16)f;
    return __builtin_bit_cast(ushort_t, h);
}

// ---- phase 1: prep (wpk), conv1 (guide->x1 + partial stats), proj ------
// grid: [0,512) conv1 | [512,1024) proj | [1024,1132) prep
__global__ __launch_bounds__(256) void k_phase1(
    const float* __restrict__ guide, const float* __restrict__ w1,
    const float* __restrict__ feat, const float* __restrict__ pw,
    const float* __restrict__ w2, const float* __restrict__ kw1,
    ushort_t* __restrict__ x1, ushort_t* __restrict__ fs,
    ushort_t* __restrict__ wpk, float* __restrict__ part1)
{
    __shared__ float smu[2080];
    int tid = threadIdx.x;
    int blk = blockIdx.x;

    if (blk < 512) {
        // ---- conv1: guide 3->32, LDS-tiled, out bf16 NHWC ----
        int b = blk >> 8;
        int tile = blk & 255;
        int ty0 = (tile >> 4) << 4, tx0 = (tile & 15) << 4;

        for (int i = tid; i < 972; i += 256) {
            int c = i / 324;
            int rem = i - c * 324;
            int r = rem / 18, cl = rem - r * 18;
            int yy = ty0 + r - 1, xx = tx0 + cl - 1;
            float v = 0.f;
            if (yy >= 0 && yy < 256 && xx >= 0 && xx < 256)
                v = guide[((b * 3 + c) * 256 + yy) * 256 + xx];
            smu[c * 342 + r * 19 + cl] = v;
        }
        __syncthreads();

        int r = tid >> 4, cl = tid & 15;
        float t[27];
#pragma unroll
        for (int c = 0; c < 3; ++c)
#pragma unroll
            for (int ky = 0; ky < 3; ++ky)
#pragma unroll
                for (int kx = 0; kx < 3; ++kx)
                    t[c * 9 + ky * 3 + kx] = smu[c * 342 + (r + ky) * 19 + cl + kx];
        int y = ty0 + r, x = tx0 + cl;
        ushort_t pk[32];
#pragma unroll 4
        for (int e = 0; e < 32; ++e) {
            float acc = 0.f;
#pragma unroll
            for (int k = 0; k < 27; ++k)
                acc += t[k] * w1[e * 27 + k];
            pk[e] = f2bf(acc);
        }
        ushort_t* dst = x1 + ((size_t)(b * 65536 + y * 256 + x)) * 32;
#pragma unroll
        for (int h = 0; h < 4; ++h)
            *(uint4*)(dst + h * 8) = *(uint4*)(pk + h * 8);

        // ---- per-block partial stats of the bf16-rounded tile ----
        float s[32], q[32];
#pragma unroll
        for (int e = 0; e < 32; ++e) {
            float v = bf2f(pk[e]);
            s[e] = v; q[e] = v * v;
        }
#pragma unroll
        for (int off = 32; off; off >>= 1) {
#pragma unroll
            for (int e = 0; e < 32; ++e) {
                s[e] += __shfl_xor(s[e], off, 64);
                q[e] += __shfl_xor(q[e], off, 64);
            }
        }
        int wv = tid >> 6, ln = tid & 63;
        __syncthreads();
        if (ln == 0) {
#pragma unroll
            for (int e = 0; e < 32; ++e) {
                smu[wv * 64 + e] = s[e];
                smu[wv * 64 + 32 + e] = q[e];
            }
        }
        __syncthreads();
        if (tid < 64)
            part1[(size_t)blk * 64 + tid] =
                smu[tid] + smu[64 + tid] + smu[128 + tid] + smu[192 + tid];
    } else if (blk < 1024) {
        // ---- 1x1 proj at lowres -> fs bf16 NHWC ----
        unsigned pix0 = (blk - 512) * 64u;
        int p = tid & 63, q = tid >> 6;
        unsigned pix = pix0 + p;
        int x = pix & 127, y = (pix >> 7) & 127, b = pix >> 14;
        float acc[8];
#pragma unroll
        for (int e = 0; e < 8; ++e) acc[e] = 0.f;
        const float* fb = feat + ((size_t)b << 21) + y * 128 + x;
#pragma unroll 4
        for (int c = 0; c < 128; ++c) {
            float v = fb[(size_t)c << 14];
#pragma unroll
            for (int e = 0; e < 8; ++e)
                acc[e] += v * pw[(q * 8 + e) * 128 + c];
        }
#pragma unroll
        for (int e = 0; e < 8; ++e)
            smu[(q * 8 + e) * 65 + p] = fmaxf(acc[e], 0.f);
        __syncthreads();
        {
            int px = tid >> 2, c8 = tid & 3;
            ushort_t pk[8];
#pragma unroll
            for (int j = 0; j < 8; ++j) pk[j] = f2bf(smu[(c8 * 8 + j) * 65 + px]);
            unsigned gp = pix0 + px;
            *(uint4*)(fs + (size_t)gp * 32 + c8 * 8) = *(uint4*)pk;
        }
    } else {
        // ---- weight prep: pack w2, kw1 into B-fragment order, bf16 ----
        int i = (blk - 1024) * 256 + tid;     // 0..27647
        if (i < 9216) {
            int j = i & 7, l = (i >> 3) & 63, nt = (i >> 9) & 1, t = i >> 10;
            int e = nt * 16 + (l & 15);
            int k = (l >> 4) * 8 + j;
            wpk[i] = f2bf(w2[(e * 32 + k) * 9 + t]);
        } else {
            int i2 = i - 9216;
            int j = i2 & 7, l = (i2 >> 3) & 63, nt = (i2 >> 9) & 1;
            int kk = (i2 >> 10) & 1, t = i2 >> 11;
            int e = nt * 16 + (l & 15);
            int k = kk * 32 + (l >> 4) * 8 + j;
            wpk[i] = f2bf(kw1[(e * 64 + k) * 9 + t]);
        }
    }
}

// ---- ab: reduce part[512][64] -> a,b coefficients ----------------------
__global__ __launch_bounds__(256) void k_ab(
    const float* __restrict__ part, const float* __restrict__ gamma,
    const float* __restrict__ beta, float* __restrict__ ab)
{
    __shared__ float fin[4][64];
    __shared__ float tot[64];
    int t = threadIdx.x;
    int c = t & 63, seg = t >> 6;
    float s = 0.f;
    const float* p = part + (size_t)seg * 128 * 64 + c;
#pragma unroll 4
    for (int b = 0; b < 128; ++b) s += p[(size_t)b * 64];
    fin[seg][c] = s;
    __syncthreads();
    if (t < 64) tot[t] = fin[0][t] + fin[1][t] + fin[2][t] + fin[3][t];
    __syncthreads();
    if (t < 32) {
        float S = tot[t], SS = tot[32 + t];
        const float n = 131072.f;
        float mean = S / n;
        float var = SS / n - mean * mean;
        float a = gamma[t] * rsqrtf(var + EPS);
        ab[t] = a;
        ab[32 + t] = beta[t] - mean * a;
    }
}

// ---- conv2: bnrelu(x1) 32->32, bf16 MFMA + partial stats of x2 ---------
__global__ __launch_bounds__(256) void k_conv2_m(
    const ushort_t* __restrict__ x1, const float* __restrict__ ab1,
    const ushort_t* __restrict__ w2pk, ushort_t* __restrict__ x2,
    float* __restrict__ part2)
{
    __shared__ __align__(16) char lds[20736];   // At: 324 px * 32 ch bf16
    int tid = threadIdx.x;
    int b = blockIdx.x >> 8, tile = blockIdx.x & 255;
    int ty0 = (tile >> 4) << 4, tx0 = (tile & 15) << 4;

    for (int i = tid; i < 1296; i += 256) {
        int px = i >> 2, c8 = i & 3;
        int r = px / 18, cl = px - r * 18;
        int yy = ty0 + r - 1, xx = tx0 + cl - 1;
        ushort_t pk[8];
        if (yy >= 0 && yy < 256 && xx >= 0 && xx < 256) {
            const ushort_t* src = x1 + ((size_t)(b * 65536 + yy * 256 + xx)) * 32 + c8 * 8;
            uint4 raw = *(const uint4*)src;
            const ushort_t* rs = (const ushort_t*)&raw;
#pragma unroll
            for (int j = 0; j < 8; ++j) {
                int c = c8 * 8 + j;
                pk[j] = f2bf(fmaxf(ab1[c] * bf2f(rs[j]) + ab1[32 + c], 0.f));
            }
        } else {
#pragma unroll
            for (int j = 0; j < 8; ++j) pk[j] = 0;
        }
        *(uint4*)(lds + swz(px * 64 + c8 * 16)) = *(uint4*)pk;
    }
    __syncthreads();

    int w = tid >> 6, l = tid & 63, lm = l & 15, lg = l >> 4;
    f32x4 acc[4][2] = {};
    const short8v* gB = (const short8v*)w2pk;
#pragma unroll
    for (int t = 0; t < 9; ++t) {
        int ky = t / 3, kx = t % 3;
        short8v B0 = gB[(t * 2 + 0) * 64 + l];
        short8v B1 = gB[(t * 2 + 1) * 64 + l];
#pragma unroll
        for (int m = 0; m < 4; ++m) {
            int px = (w * 4 + m + ky) * 18 + lm + kx;
            short8v A = *(const short8v*)(lds + swz(px * 64 + lg * 16));
            acc[m][0] = __builtin_amdgcn_mfma_f32_16x16x32_bf16(A, B0, acc[m][0], 0, 0, 0);
            acc[m][1] = __builtin_amdgcn_mfma_f32_16x16x32_bf16(A, B1, acc[m][1], 0, 0, 0);
        }
    }

    // per-thread stats of the bf16-rounded outputs (ch lm and lm+16)
    float sl = 0.f, sh = 0.f, ql = 0.f, qh = 0.f;
#pragma unroll
    for (int m = 0; m < 4; ++m)
#pragma unroll
        for (int rg = 0; rg < 4; ++rg) {
            float vlo = bf2f(f2bf(acc[m][0][rg]));
            float vhi = bf2f(f2bf(acc[m][1][rg]));
            sl += vlo; ql += vlo * vlo;
            sh += vhi; qh += vhi * vhi;
        }
#pragma unroll
    for (int off = 16; off <= 32; off <<= 1) {
        sl += __shfl_xor(sl, off, 64); sh += __shfl_xor(sh, off, 64);
        ql += __shfl_xor(ql, off, 64); qh += __shfl_xor(qh, off, 64);
    }

    // epilogue: dump to LDS (bf16 [px][32]) then coalesced global write
    __syncthreads();
#pragma unroll
    for (int m = 0; m < 4; ++m)
#pragma unroll
        for (int nt = 0; nt < 2; ++nt)
#pragma unroll
            for (int rg = 0; rg < 4; ++rg) {
                int px = (w * 4 + m) * 16 + lg * 4 + rg;
                int e = nt * 16 + lm;
                *(ushort_t*)(lds + swz(px * 64 + e * 2)) = f2bf(acc[m][nt][rg]);
            }
    __syncthreads();
    {
        int px = tid, r = px >> 4, cl = px & 15;
        int yy = ty0 + r, xx = tx0 + cl;
        ushort_t* dst = x2 + ((size_t)(b * 65536 + yy * 256 + xx)) * 32;
#pragma unroll
        for (int h = 0; h < 4; ++h)
            *(uint4*)(dst + h * 8) = *(uint4*)(lds + swz(px * 64 + h * 16));
    }

    // combine wave partials -> part2[blk][64]
    __syncthreads();
    float* redf = (float*)lds;
    if (l < 16) {
        redf[w * 64 + 0 * 16 + lm] = sl;
        redf[w * 64 + 1 * 16 + lm] = sh;
        redf[w * 64 + 2 * 16 + lm] = ql;
        redf[w * 64 + 3 * 16 + lm] = qh;
    }
    __syncthreads();
    if (tid < 64) {
        int lmq = tid & 15, quant = tid >> 4;
        float tq = redf[0 * 64 + quant * 16 + lmq] + redf[1 * 64 + quant * 16 + lmq]
                 + redf[2 * 64 + quant * 16 + lmq] + redf[3 * 64 + quant * 16 + lmq];
        int col = (quant < 2) ? quant * 16 + lmq : 32 + (quant - 2) * 16 + lmq;
        part2[(size_t)blockIdx.x * 64 + col] = tq;
    }
}

// ---- kernel head: conv3x3 64->32 (MFMA) + ReLU + 1x1->9 + softmax ------
// writes kern48: [b*16384 + ly*128 + lx][sub(=ry*2+rx)][12]
__global__ __launch_bounds__(256) void k_kern_m(
    const ushort_t* __restrict__ x2, const float* __restrict__ ab2,
    const ushort_t* __restrict__ fs, const ushort_t* __restrict__ kw1pk,
    const float* __restrict__ kw2, const float* __restrict__ kb2,
    float* __restrict__ kern48)
{
    __shared__ __align__(16) char lds[41472];   // comb: 324 px * 64 ch bf16
    int tid = threadIdx.x;
    int b = blockIdx.x >> 8, tile = blockIdx.x & 255;
    int ty0 = (tile >> 4) << 4, tx0 = (tile & 15) << 4;

    for (int i = tid; i < 2592; i += 256) {     // 324 px * 8 chunks
        int px = i >> 3, c8 = i & 7;
        int r = px / 18, cl = px - r * 18;
        int yy = ty0 + r - 1, xx = tx0 + cl - 1;
        ushort_t pk[8];
        if (yy >= 0 && yy < 256 && xx >= 0 && xx < 256) {
            if (c8 < 4) {
                const ushort_t* src = x2 + ((size_t)(b * 65536 + yy * 256 + xx)) * 32 + c8 * 8;
                uint4 raw = *(const uint4*)src;
                const ushort_t* rs = (const ushort_t*)&raw;
#pragma unroll
                for (int j = 0; j < 8; ++j) {
                    int c = c8 * 8 + j;
                    pk[j] = f2bf(fmaxf(ab2[c] * bf2f(rs[j]) + ab2[32 + c], 0.f));
                }
            } else {
                const ushort_t* src = fs + ((size_t)(b * 16384 + (yy >> 1) * 128 + (xx >> 1))) * 32 + (c8 - 4) * 8;
                *(uint4*)pk = *(const uint4*)src;
            }
        } else {
#pragma unroll
            for (int j = 0; j < 8; ++j) pk[j] = 0;
        }
        *(uint4*)(lds + swz(px * 128 + c8 * 16)) = *(uint4*)pk;
    }
    __syncthreads();

    int w = tid >> 6, l = tid & 63, lm = l & 15, lg = l >> 4;
    f32x4 acc[4][2] = {};
    const short8v* gB = (const short8v*)kw1pk;
#pragma unroll
    for (int t = 0; t < 9; ++t) {
        int ky = t / 3, kx = t % 3;
#pragma unroll
        for (int kk = 0; kk < 2; ++kk) {
            short8v B0 = gB[(t * 4 + kk * 2 + 0) * 64 + l];
            short8v B1 = gB[(t * 4 + kk * 2 + 1) * 64 + l];
#pragma unroll
            for (int m = 0; m < 4; ++m) {
                int px = (w * 4 + m + ky) * 18 + lm + kx;
                short8v A = *(const short8v*)(lds + swz(px * 128 + kk * 64 + lg * 16));
                acc[m][0] = __builtin_amdgcn_mfma_f32_16x16x32_bf16(A, B0, acc[m][0], 0, 0, 0);
                acc[m][1] = __builtin_amdgcn_mfma_f32_16x16x32_bf16(A, B1, acc[m][1], 0, 0, 0);
            }
        }
    }
    __syncthreads();
#pragma unroll
    for (int m = 0; m < 4; ++m)
#pragma unroll
        for (int nt = 0; nt < 2; ++nt)
#pragma unroll
            for (int rg = 0; rg < 4; ++rg) {
                int px = (w * 4 + m) * 16 + lg * 4 + rg;
                int e = nt * 16 + lm;
                *(float*)(lds + swz(px * 128 + e * 4)) = acc[m][nt][rg];
            }
    __syncthreads();
    {
        int px = tid, r = px >> 4, cl = px & 15;
        float v[32];
#pragma unroll
        for (int h = 0; h < 8; ++h) {
            float4 q = *(const float4*)(lds + swz(px * 128 + h * 16));
            v[h * 4 + 0] = q.x; v[h * 4 + 1] = q.y; v[h * 4 + 2] = q.z; v[h * 4 + 3] = q.w;
        }
        float z[9];
#pragma unroll
        for (int i = 0; i < 9; ++i) z[i] = kb2[i];
#pragma unroll
        for (int e = 0; e < 32; ++e) {
            float ae = fmaxf(v[e], 0.f);
#pragma unroll
            for (int i = 0; i < 9; ++i)
                z[i] += ae * kw2[i * 32 + e];
        }
        float m = z[0];
#pragma unroll
        for (int i = 1; i < 9; ++i) m = fmaxf(m, z[i]);
        float sum = 0.f;
#pragma unroll
        for (int i = 0; i < 9; ++i) { z[i] = expf(z[i] - m); sum += z[i]; }
        float inv = 1.f / sum;
#pragma unroll
        for (int i = 0; i < 9; ++i) z[i] *= inv;
        int yq = ty0 + r, xq = tx0 + cl;
        size_t gp = ((size_t)(b * 16384 + (yq >> 1) * 128 + (xq >> 1))) * 48
                  + ((yq & 1) * 2 + (xq & 1)) * 12;
        float4* dp = (float4*)(kern48 + gp);
        float4 o0, o1, o2;
        o0.x = z[0]; o0.y = z[1]; o0.z = z[2]; o0.w = z[3];
        o1.x = z[4]; o1.y = z[5]; o1.z = z[6]; o1.w = z[7];
        o2.x = z[8]; o2.y = 0.f;  o2.z = 0.f;  o2.w = 0.f;
        dp[0] = o0; dp[1] = o1; dp[2] = o2;
    }
}

// ---- CARAFE reassembly: 8-ch chunks, replication-collapsed taps --------
__global__ __launch_bounds__(256) void k_out2(
    const float* __restrict__ feat, const float* __restrict__ kern48,
    float* __restrict__ out)
{
    __shared__ __align__(16) char smf[10368];   // 324 px * 8 ch fp32
    int tid = threadIdx.x;
    int blk = blockIdx.x;                 // 2048 = b(2) * chunk(16) * tile(64)
    int b = blk >> 10;
    int chunk = (blk >> 6) & 15;
    int tile = blk & 63;
    int ty0 = (tile >> 3) << 4, tx0 = (tile & 7) << 4;

    for (int i = tid; i < 648; i += 256) {
        int c4 = i / 324, px = i - c4 * 324;
        int r = px / 18, cl = px - r * 18;
        int yy = ty0 + r - 1, xx = tx0 + cl - 1;
        float4 v; v.x = 0.f; v.y = 0.f; v.z = 0.f; v.w = 0.f;
        if (yy >= 0 && yy < 128 && xx >= 0 && xx < 128) {
            int c0 = chunk * 8 + c4 * 4;
            size_t base = ((size_t)(b * 128 + c0) << 14) + yy * 128 + xx;
            v.x = feat[base];
            v.y = feat[base + (1 << 14)];
            v.z = feat[base + (2 << 14)];
            v.w = feat[base + (3 << 14)];
        }
        *(float4*)(smf + swz(px * 32 + c4 * 16)) = v;
    }
    __syncthreads();

    int r = tid >> 4, cl = tid & 15;
    int y = ty0 + r, x = tx0 + cl;

    const float* kp = kern48 + ((size_t)(b * 16384 + y * 128 + x)) * 48;
    float k4[2][2][9];
#pragma unroll
    for (int ry = 0; ry < 2; ++ry)
#pragma unroll
        for (int rx = 0; rx < 2; ++rx) {
            const float4* q = (const float4*)(kp + (ry * 2 + rx) * 12);
            float4 q0 = q[0], q1 = q[1], q2 = q[2];
            k4[ry][rx][0] = q0.x; k4[ry][rx][1] = q0.y; k4[ry][rx][2] = q0.z;
            k4[ry][rx][3] = q0.w; k4[ry][rx][4] = q1.x; k4[ry][rx][5] = q1.y;
            k4[ry][rx][6] = q1.z; k4[ry][rx][7] = q1.w; k4[ry][rx][8] = q2.x;
        }

    const int jmap[2][3] = { {0, 1, 1}, {1, 1, 2} };
    float acc[8][4];
#pragma unroll
    for (int ch = 0; ch < 8; ++ch)
#pragma unroll
        for (int o = 0; o < 4; ++o) acc[ch][o] = 0.f;

#pragma unroll
    for (int ny = 0; ny < 3; ++ny)
#pragma unroll
        for (int nx = 0; nx < 3; ++nx) {
            float co[2][2];
#pragma unroll
            for (int ry = 0; ry < 2; ++ry)
#pragma unroll
                for (int rx = 0; rx < 2; ++rx) {
                    float s = 0.f;
#pragma unroll
                    for (int a = 0; a < 3; ++a)
#pragma unroll
                        for (int bq = 0; bq < 3; ++bq)
                            if (jmap[ry][a] == ny && jmap[rx][bq] == nx)
                                s += k4[ry][rx][a * 3 + bq];
                    co[ry][rx] = s;
                }
            int px = (r + ny) * 18 + cl + nx;
            float4 f0 = *(const float4*)(smf + swz(px * 32));
            float4 f1 = *(const float4*)(smf + swz(px * 32 + 16));
            float fv[8] = { f0.x, f0.y, f0.z, f0.w, f1.x, f1.y, f1.z, f1.w };
#pragma unroll
            for (int ch = 0; ch < 8; ++ch) {
                acc[ch][0] += co[0][0] * fv[ch];
                acc[ch][1] += co[0][1] * fv[ch];
                acc[ch][2] += co[1][0] * fv[ch];
                acc[ch][3] += co[1][1] * fv[ch];
            }
        }

#pragma unroll
    for (int ch = 0; ch < 8; ++ch) {
        int c = chunk * 8 + ch;
        size_t base = (((size_t)(b * 128 + c) * 256 + 2 * y) * 256 + 2 * x);
        float2 o0, o1;
        o0.x = acc[ch][0]; o0.y = acc[ch][1];
        o1.x = acc[ch][2]; o1.y = acc[ch][3];
        *(float2*)(out + base) = o0;
        *(float2*)(out + base + 256) = o1;
    }
}

extern "C" void kernel_launch(void* const* d_in, const int* in_sizes, int n_in,
                              void* d_out, int out_size, void* d_ws, size_t ws_size,
                              hipStream_t stream)
{
    const float* feat  = (const float*)d_in[0];
    const float* guide = (const float*)d_in[1];
    const float* g_w1  = (const float*)d_in[2];
    const float* g_g1  = (const float*)d_in[3];
    const float* g_b1  = (const float*)d_in[4];
    const float* g_w2  = (const float*)d_in[5];
    const float* g_g2  = (const float*)d_in[6];
    const float* g_b2  = (const float*)d_in[7];
    const float* p_w   = (const float*)d_in[8];
    const float* k_w1  = (const float*)d_in[9];
    const float* k_w2  = (const float*)d_in[10];
    const float* k_b2  = (const float*)d_in[11];

    float* out = (float*)d_out;

    // scratch inside d_out (64 MB), all dead before k_out2 writes:
    ushort_t* x1 = (ushort_t*)out;                    // bytes [0, 8.4MB)
    ushort_t* x2 = (ushort_t*)(out + 2097152);        // bytes [8.4MB, 16.8MB)
    float* part1 = out + 8388608;                     // byte 33554432, 128KB
    float* part2 = part1 + 32768;                     // 128KB
    float* ab1   = part2 + 32768;                     // 256B
    float* ab2   = ab1 + 64;                          // 256B

    // workspace layout (d_ws, proven-safe 8.45MB footprint)
    float*    kern48 = (float*)d_ws;                  // 1,572,864 f32 (6.3MB)
    ushort_t* fs     = (ushort_t*)((char*)d_ws + 6291456);   // 1,048,576 bf16
    ushort_t* wpk    = (ushort_t*)((char*)d_ws + 8388608);   // 27,648 bf16
    ushort_t* w2pk   = wpk;
    ushort_t* kw1pk  = wpk + 9216;

    k_phase1<<<1132, 256, 0, stream>>>(guide, g_w1, feat, p_w, g_w2, k_w1,
                                       x1, fs, wpk, part1);
    k_ab<<<1, 256, 0, stream>>>(part1, g_g1, g_b1, ab1);
    k_conv2_m<<<512, 256, 0, stream>>>(x1, ab1, w2pk, x2, part2);
    k_ab<<<1, 256, 0, stream>>>(part2, g_g2, g_b2, ab2);
    k_kern_m<<<512, 256, 0, stream>>>(x2, ab2, fs, kw1pk, k_w2, k_b2, kern48);
    k_out2<<<2048, 256, 0, stream>>>(feat, kern48, out);
}

// Round 8
// 98.486 us; speedup vs baseline: 1.2243x; 1.2243x over previous
//
#include <hip/hip_runtime.h>
#include <hip/hip_bf16.h>

#define EPS 1e-5f

// dims: feat (2,128,128,128) f32 NCHW, guide (2,3,256,256) f32 NCHW,
// out (2,128,256,256) f32 NCHW. E=32, K=3, k2=9. H2=W2=256.
// x1,x2 bf16 NHWC (2,256,256,32) in d_out; fs bf16 NHWC (2,128,128,32),
// kern48 f32 [lowres px][4 subpx][12], packed weights, stats in d_ws.

typedef unsigned short ushort_t;
typedef __attribute__((ext_vector_type(8))) short short8v;   // 8 bf16 = 4 VGPR
typedef __attribute__((ext_vector_type(4))) float f32x4;

__device__ __forceinline__ int swz(int b) { return b ^ (((b >> 7) & 7) << 4); }
__device__ __forceinline__ float bf2f(ushort_t u) {
    unsigned int t = ((unsigned int)u) << 16;
    return __builtin_bit_cast(float, t);
}
__device__ __forceinline__ ushort_t f2bf(float f) {   // RNE via HW cvt
    __hip_bfloat16 h = (__hip_bfloat16)f;
    return __builtin_bit_cast(ushort_t, h);
}

// ---- phase 1: conv1 (guide->x1) + weight prep (w2,kw1,pw -> bf16 frags) -
// grid: [0,512) conv1 | [512,636) prep
__global__ __launch_bounds__(256) void k_phase1(
    const float* __restrict__ guide, const float* __restrict__ w1,
    const float* __restrict__ w2, const float* __restrict__ kw1,
    const float* __restrict__ pw,
    ushort_t* __restrict__ x1, ushort_t* __restrict__ wpk)
{
    __shared__ float smu[1026];
    int tid = threadIdx.x;
    int blk = blockIdx.x;

    if (blk < 512) {
        // ---- conv1: guide 3->32, LDS-tiled, out bf16 NHWC ----
        int b = blk >> 8;
        int tile = blk & 255;
        int ty0 = (tile >> 4) << 4, tx0 = (tile & 15) << 4;

        for (int i = tid; i < 972; i += 256) {
            int c = i / 324;
            int rem = i - c * 324;
            int r = rem / 18, cl = rem - r * 18;
            int yy = ty0 + r - 1, xx = tx0 + cl - 1;
            float v = 0.f;
            if (yy >= 0 && yy < 256 && xx >= 0 && xx < 256)
                v = guide[((b * 3 + c) * 256 + yy) * 256 + xx];
            smu[c * 342 + r * 19 + cl] = v;
        }
        __syncthreads();

        int r = tid >> 4, cl = tid & 15;
        float t[27];
#pragma unroll
        for (int c = 0; c < 3; ++c)
#pragma unroll
            for (int ky = 0; ky < 3; ++ky)
#pragma unroll
                for (int kx = 0; kx < 3; ++kx)
                    t[c * 9 + ky * 3 + kx] = smu[c * 342 + (r + ky) * 19 + cl + kx];
        int y = ty0 + r, x = tx0 + cl;
        ushort_t pk[32];
#pragma unroll 4
        for (int e = 0; e < 32; ++e) {
            float acc = 0.f;
#pragma unroll
            for (int k = 0; k < 27; ++k)
                acc += t[k] * w1[e * 27 + k];
            pk[e] = f2bf(acc);
        }
        ushort_t* dst = x1 + ((size_t)(b * 65536 + y * 256 + x)) * 32;
#pragma unroll
        for (int h = 0; h < 4; ++h)
            *(uint4*)(dst + h * 8) = *(uint4*)(pk + h * 8);
    } else {
        // ---- weight prep: w2 | kw1 | pw into B-fragment order, bf16 ----
        int i = (blk - 512) * 256 + tid;     // 0..31743
        if (i < 9216) {
            int j = i & 7, l = (i >> 3) & 63, nt = (i >> 9) & 1, t = i >> 10;
            int e = nt * 16 + (l & 15);
            int k = (l >> 4) * 8 + j;
            wpk[i] = f2bf(w2[(e * 32 + k) * 9 + t]);
        } else if (i < 27648) {
            int i2 = i - 9216;
            int j = i2 & 7, l = (i2 >> 3) & 63, nt = (i2 >> 9) & 1;
            int kk = (i2 >> 10) & 1, t = i2 >> 11;
            int e = nt * 16 + (l & 15);
            int k = kk * 32 + (l >> 4) * 8 + j;
            wpk[i] = f2bf(kw1[(e * 64 + k) * 9 + t]);
        } else {
            int i3 = i - 27648;                  // pwpk: [ks][nt][l][j]
            int j = i3 & 7, l = (i3 >> 3) & 63, nt = (i3 >> 9) & 1, ks = i3 >> 10;
            int e = nt * 16 + (l & 15);
            int c = ks * 32 + (l >> 4) * 8 + j;
            wpk[i] = f2bf(pw[e * 128 + c]);
        }
    }
}

// ---- stats partial: 256 blocks x 512 px -> part[256][64] ---------------
__global__ __launch_bounds__(256) void k_statsP(
    const ushort_t* __restrict__ x, float* __restrict__ part)
{
    int tid = threadIdx.x, bk = blockIdx.x;
    int p = tid >> 4, c2 = tid & 15;
    float s0 = 0.f, ss0 = 0.f, s1 = 0.f, ss1 = 0.f;
    const ushort_t* base = x + ((size_t)bk * 512) * 32 + c2 * 2;
    for (int i = 0; i < 32; ++i) {
        unsigned int v = *(const unsigned int*)(base + (size_t)(i * 16 + p) * 32);
        float a = bf2f((ushort_t)(v & 0xffff));
        float c = bf2f((ushort_t)(v >> 16));
        s0 += a; ss0 += a * a; s1 += c; ss1 += c * c;
    }
    __shared__ float red[256][4];
    red[tid][0] = s0; red[tid][1] = ss0; red[tid][2] = s1; red[tid][3] = ss1;
    __syncthreads();
    if (tid < 64) {
        int c2s = tid & 15, vs = tid >> 4;
        float t = 0.f;
        for (int pp = 0; pp < 16; ++pp) t += red[pp * 16 + c2s][vs];
        part[bk * 64 + c2s * 4 + vs] = t;
    }
}

__global__ void k_statsF(
    const float* __restrict__ part, const float* __restrict__ gamma,
    const float* __restrict__ beta, float* __restrict__ ab)
{
    __shared__ float tot[64];
    int t = threadIdx.x;     // 64 threads
    float s = 0.f;
    for (int bk = 0; bk < 256; ++bk) s += part[bk * 64 + t];
    tot[t] = s;
    __syncthreads();
    if (t < 32) {
        float S  = tot[(t >> 1) * 4 + (t & 1) * 2];
        float SS = tot[(t >> 1) * 4 + (t & 1) * 2 + 1];
        const float n = 131072.f;
        float mean = S / n;
        float var = SS / n - mean * mean;
        float a = gamma[t] * rsqrtf(var + EPS);
        ab[t] = a;
        ab[32 + t] = beta[t] - mean * a;
    }
}

// ---- conv2 (blocks 0..511) + proj MFMA (blocks 512..767) ---------------
__global__ __launch_bounds__(256) void k_conv2p(
    const ushort_t* __restrict__ x1, const float* __restrict__ ab1,
    const ushort_t* __restrict__ w2pk, ushort_t* __restrict__ x2,
    const float* __restrict__ feat, const ushort_t* __restrict__ pwpk,
    ushort_t* __restrict__ fs)
{
    __shared__ __align__(16) char lds[32768];
    int tid = threadIdx.x;
    int blk = blockIdx.x;

    if (blk < 512) {
        // ---- conv2: bnrelu(x1) 32->32, bf16 MFMA implicit GEMM ----
        int b = blk >> 8, tile = blk & 255;
        int ty0 = (tile >> 4) << 4, tx0 = (tile & 15) << 4;

        for (int i = tid; i < 1296; i += 256) {
            int px = i >> 2, c8 = i & 3;
            int r = px / 18, cl = px - r * 18;
            int yy = ty0 + r - 1, xx = tx0 + cl - 1;
            ushort_t pk[8];
            if (yy >= 0 && yy < 256 && xx >= 0 && xx < 256) {
                const ushort_t* src = x1 + ((size_t)(b * 65536 + yy * 256 + xx)) * 32 + c8 * 8;
                uint4 raw = *(const uint4*)src;
                const ushort_t* rs = (const ushort_t*)&raw;
#pragma unroll
                for (int j = 0; j < 8; ++j) {
                    int c = c8 * 8 + j;
                    pk[j] = f2bf(fmaxf(ab1[c] * bf2f(rs[j]) + ab1[32 + c], 0.f));
                }
            } else {
#pragma unroll
                for (int j = 0; j < 8; ++j) pk[j] = 0;
            }
            *(uint4*)(lds + swz(px * 64 + c8 * 16)) = *(uint4*)pk;
        }
        __syncthreads();

        int w = tid >> 6, l = tid & 63, lm = l & 15, lg = l >> 4;
        f32x4 acc[4][2] = {};
        const short8v* gB = (const short8v*)w2pk;
#pragma unroll
        for (int t = 0; t < 9; ++t) {
            int ky = t / 3, kx = t % 3;
            short8v B0 = gB[(t * 2 + 0) * 64 + l];
            short8v B1 = gB[(t * 2 + 1) * 64 + l];
#pragma unroll
            for (int m = 0; m < 4; ++m) {
                int px = (w * 4 + m + ky) * 18 + lm + kx;
                short8v A = *(const short8v*)(lds + swz(px * 64 + lg * 16));
                acc[m][0] = __builtin_amdgcn_mfma_f32_16x16x32_bf16(A, B0, acc[m][0], 0, 0, 0);
                acc[m][1] = __builtin_amdgcn_mfma_f32_16x16x32_bf16(A, B1, acc[m][1], 0, 0, 0);
            }
        }
        __syncthreads();
#pragma unroll
        for (int m = 0; m < 4; ++m)
#pragma unroll
            for (int nt = 0; nt < 2; ++nt)
#pragma unroll
                for (int rg = 0; rg < 4; ++rg) {
                    int px = (w * 4 + m) * 16 + lg * 4 + rg;
                    int e = nt * 16 + lm;
                    *(ushort_t*)(lds + swz(px * 64 + e * 2)) = f2bf(acc[m][nt][rg]);
                }
        __syncthreads();
        {
            int px = tid, r = px >> 4, cl = px & 15;
            int yy = ty0 + r, xx = tx0 + cl;
            ushort_t* dst = x2 + ((size_t)(b * 65536 + yy * 256 + xx)) * 32;
#pragma unroll
            for (int h = 0; h < 4; ++h)
                *(uint4*)(dst + h * 8) = *(uint4*)(lds + swz(px * 64 + h * 16));
        }
    } else {
        // ---- proj: 1x1 conv 128->32 as MFMA GEMM, one lowres row/block --
        int row = blk - 512;              // 0..255
        int b = row >> 7, yl = row & 127;

        // stage feat[b, :, yl, :] -> LDS bf16 [128 px][128 ch], swizzled
        int x = tid & 127, cg = tid >> 7;
        const float* fb = feat + ((size_t)b << 21) + yl * 128 + x;
#pragma unroll
        for (int p = 0; p < 8; ++p) {
            int c0 = p * 16 + cg * 8;
            ushort_t pk[8];
#pragma unroll
            for (int j = 0; j < 8; ++j)
                pk[j] = f2bf(fb[(size_t)(c0 + j) << 14]);
            *(uint4*)(lds + swz(x * 256 + c0 * 2)) = *(uint4*)pk;
        }
        __syncthreads();

        int w = tid >> 6, l = tid & 63, lm = l & 15, lg = l >> 4;
        int px0 = w * 32;
        f32x4 acc[2][2] = {};
        const short8v* gB = (const short8v*)pwpk;
#pragma unroll
        for (int ks = 0; ks < 4; ++ks) {
            short8v B0 = gB[(ks * 2 + 0) * 64 + l];
            short8v B1 = gB[(ks * 2 + 1) * 64 + l];
#pragma unroll
            for (int m = 0; m < 2; ++m) {
                short8v A = *(const short8v*)(
                    lds + swz((px0 + m * 16 + lm) * 256 + ks * 64 + lg * 16));
                acc[m][0] = __builtin_amdgcn_mfma_f32_16x16x32_bf16(A, B0, acc[m][0], 0, 0, 0);
                acc[m][1] = __builtin_amdgcn_mfma_f32_16x16x32_bf16(A, B1, acc[m][1], 0, 0, 0);
            }
        }
        __syncthreads();
        // relu + dump bf16 [128 px][32 e]
#pragma unroll
        for (int m = 0; m < 2; ++m)
#pragma unroll
            for (int nt = 0; nt < 2; ++nt)
#pragma unroll
                for (int rg = 0; rg < 4; ++rg) {
                    int px = px0 + m * 16 + lg * 4 + rg;
                    int e = nt * 16 + lm;
                    *(ushort_t*)(lds + swz(px * 64 + e * 2)) =
                        f2bf(fmaxf(acc[m][nt][rg], 0.f));
                }
        __syncthreads();
        if (tid < 128) {
            ushort_t* dst = fs + ((size_t)(b * 16384 + yl * 128 + tid)) * 32;
#pragma unroll
            for (int h = 0; h < 4; ++h)
                *(uint4*)(dst + h * 8) = *(uint4*)(lds + swz(tid * 64 + h * 16));
        }
    }
}

// ---- kernel head: conv3x3 64->32 (MFMA) + ReLU + 1x1->9 + softmax ------
// writes kern48: [b*16384 + ly*128 + lx][sub(=ry*2+rx)][12]
__global__ __launch_bounds__(256) void k_kern_m(
    const ushort_t* __restrict__ x2, const float* __restrict__ ab2,
    const ushort_t* __restrict__ fs, const ushort_t* __restrict__ kw1pk,
    const float* __restrict__ kw2, const float* __restrict__ kb2,
    float* __restrict__ kern48)
{
    __shared__ __align__(16) char lds[41472];   // comb: 324 px * 64 ch bf16
    int tid = threadIdx.x;
    int b = blockIdx.x >> 8, tile = blockIdx.x & 255;
    int ty0 = (tile >> 4) << 4, tx0 = (tile & 15) << 4;

    for (int i = tid; i < 2592; i += 256) {     // 324 px * 8 chunks
        int px = i >> 3, c8 = i & 7;
        int r = px / 18, cl = px - r * 18;
        int yy = ty0 + r - 1, xx = tx0 + cl - 1;
        ushort_t pk[8];
        if (yy >= 0 && yy < 256 && xx >= 0 && xx < 256) {
            if (c8 < 4) {
                const ushort_t* src = x2 + ((size_t)(b * 65536 + yy * 256 + xx)) * 32 + c8 * 8;
                uint4 raw = *(const uint4*)src;
                const ushort_t* rs = (const ushort_t*)&raw;
#pragma unroll
                for (int j = 0; j < 8; ++j) {
                    int c = c8 * 8 + j;
                    pk[j] = f2bf(fmaxf(ab2[c] * bf2f(rs[j]) + ab2[32 + c], 0.f));
                }
            } else {
                const ushort_t* src = fs + ((size_t)(b * 16384 + (yy >> 1) * 128 + (xx >> 1))) * 32 + (c8 - 4) * 8;
                *(uint4*)pk = *(const uint4*)src;
            }
        } else {
#pragma unroll
            for (int j = 0; j < 8; ++j) pk[j] = 0;
        }
        *(uint4*)(lds + swz(px * 128 + c8 * 16)) = *(uint4*)pk;
    }
    __syncthreads();

    int w = tid >> 6, l = tid & 63, lm = l & 15, lg = l >> 4;
    f32x4 acc[4][2] = {};
    const short8v* gB = (const short8v*)kw1pk;
#pragma unroll
    for (int t = 0; t < 9; ++t) {
        int ky = t / 3, kx = t % 3;
#pragma unroll
        for (int kk = 0; kk < 2; ++kk) {
            short8v B0 = gB[(t * 4 + kk * 2 + 0) * 64 + l];
            short8v B1 = gB[(t * 4 + kk * 2 + 1) * 64 + l];
#pragma unroll
            for (int m = 0; m < 4; ++m) {
                int px = (w * 4 + m + ky) * 18 + lm + kx;
                short8v A = *(const short8v*)(lds + swz(px * 128 + kk * 64 + lg * 16));
                acc[m][0] = __builtin_amdgcn_mfma_f32_16x16x32_bf16(A, B0, acc[m][0], 0, 0, 0);
                acc[m][1] = __builtin_amdgcn_mfma_f32_16x16x32_bf16(A, B1, acc[m][1], 0, 0, 0);
            }
        }
    }
    __syncthreads();
#pragma unroll
    for (int m = 0; m < 4; ++m)
#pragma unroll
        for (int nt = 0; nt < 2; ++nt)
#pragma unroll
            for (int rg = 0; rg < 4; ++rg) {
                int px = (w * 4 + m) * 16 + lg * 4 + rg;
                int e = nt * 16 + lm;
                *(float*)(lds + swz(px * 128 + e * 4)) = acc[m][nt][rg];
            }
    __syncthreads();
    {
        int px = tid, r = px >> 4, cl = px & 15;
        float v[32];
#pragma unroll
        for (int h = 0; h < 8; ++h) {
            float4 q = *(const float4*)(lds + swz(px * 128 + h * 16));
            v[h * 4 + 0] = q.x; v[h * 4 + 1] = q.y; v[h * 4 + 2] = q.z; v[h * 4 + 3] = q.w;
        }
        float z[9];
#pragma unroll
        for (int i = 0; i < 9; ++i) z[i] = kb2[i];
#pragma unroll
        for (int e = 0; e < 32; ++e) {
            float ae = fmaxf(v[e], 0.f);
#pragma unroll
            for (int i = 0; i < 9; ++i)
                z[i] += ae * kw2[i * 32 + e];
        }
        float m = z[0];
#pragma unroll
        for (int i = 1; i < 9; ++i) m = fmaxf(m, z[i]);
        float sum = 0.f;
#pragma unroll
        for (int i = 0; i < 9; ++i) { z[i] = expf(z[i] - m); sum += z[i]; }
        float inv = 1.f / sum;
#pragma unroll
        for (int i = 0; i < 9; ++i) z[i] *= inv;
        int yq = ty0 + r, xq = tx0 + cl;
        size_t gp = ((size_t)(b * 16384 + (yq >> 1) * 128 + (xq >> 1))) * 48
                  + ((yq & 1) * 2 + (xq & 1)) * 12;
        float4* dp = (float4*)(kern48 + gp);
        float4 o0, o1, o2;
        o0.x = z[0]; o0.y = z[1]; o0.z = z[2]; o0.w = z[3];
        o1.x = z[4]; o1.y = z[5]; o1.z = z[6]; o1.w = z[7];
        o2.x = z[8]; o2.y = 0.f;  o2.z = 0.f;  o2.w = 0.f;
        dp[0] = o0; dp[1] = o1; dp[2] = o2;
    }
}

// ---- CARAFE reassembly: 8-ch chunks, replication-collapsed taps --------
__global__ __launch_bounds__(256) void k_out2(
    const float* __restrict__ feat, const float* __restrict__ kern48,
    float* __restrict__ out)
{
    __shared__ __align__(16) char smf[10368];   // 324 px * 8 ch fp32
    int tid = threadIdx.x;
    int blk = blockIdx.x;                 // 2048 = b(2) * chunk(16) * tile(64)
    int b = blk >> 10;
    int chunk = (blk >> 6) & 15;
    int tile = blk & 63;
    int ty0 = (tile >> 3) << 4, tx0 = (tile & 7) << 4;

    for (int i = tid; i < 648; i += 256) {
        int c4 = i / 324, px = i - c4 * 324;
        int r = px / 18, cl = px - r * 18;
        int yy = ty0 + r - 1, xx = tx0 + cl - 1;
        float4 v; v.x = 0.f; v.y = 0.f; v.z = 0.f; v.w = 0.f;
        if (yy >= 0 && yy < 128 && xx >= 0 && xx < 128) {
            int c0 = chunk * 8 + c4 * 4;
            size_t base = ((size_t)(b * 128 + c0) << 14) + yy * 128 + xx;
            v.x = feat[base];
            v.y = feat[base + (1 << 14)];
            v.z = feat[base + (2 << 14)];
            v.w = feat[base + (3 << 14)];
        }
        *(float4*)(smf + swz(px * 32 + c4 * 16)) = v;
    }
    __syncthreads();

    int r = tid >> 4, cl = tid & 15;
    int y = ty0 + r, x = tx0 + cl;

    const float* kp = kern48 + ((size_t)(b * 16384 + y * 128 + x)) * 48;
    float k4[2][2][9];
#pragma unroll
    for (int ry = 0; ry < 2; ++ry)
#pragma unroll
        for (int rx = 0; rx < 2; ++rx) {
            const float4* q = (const float4*)(kp + (ry * 2 + rx) * 12);
            float4 q0 = q[0], q1 = q[1], q2 = q[2];
            k4[ry][rx][0] = q0.x; k4[ry][rx][1] = q0.y; k4[ry][rx][2] = q0.z;
            k4[ry][rx][3] = q0.w; k4[ry][rx][4] = q1.x; k4[ry][rx][5] = q1.y;
            k4[ry][rx][6] = q1.z; k4[ry][rx][7] = q1.w; k4[ry][rx][8] = q2.x;
        }

    const int jmap[2][3] = { {0, 1, 1}, {1, 1, 2} };
    float acc[8][4];
#pragma unroll
    for (int ch = 0; ch < 8; ++ch)
#pragma unroll
        for (int o = 0; o < 4; ++o) acc[ch][o] = 0.f;

#pragma unroll
    for (int ny = 0; ny < 3; ++ny)
#pragma unroll
        for (int nx = 0; nx < 3; ++nx) {
            float co[2][2];
#pragma unroll
            for (int ry = 0; ry < 2; ++ry)
#pragma unroll
                for (int rx = 0; rx < 2; ++rx) {
                    float s = 0.f;
#pragma unroll
                    for (int a = 0; a < 3; ++a)
#pragma unroll
                        for (int bq = 0; bq < 3; ++bq)
                            if (jmap[ry][a] == ny && jmap[rx][bq] == nx)
                                s += k4[ry][rx][a * 3 + bq];
                    co[ry][rx] = s;
                }
            int px = (r + ny) * 18 + cl + nx;
            float4 f0 = *(const float4*)(smf + swz(px * 32));
            float4 f1 = *(const float4*)(smf + swz(px * 32 + 16));
            float fv[8] = { f0.x, f0.y, f0.z, f0.w, f1.x, f1.y, f1.z, f1.w };
#pragma unroll
            for (int ch = 0; ch < 8; ++ch) {
                acc[ch][0] += co[0][0] * fv[ch];
                acc[ch][1] += co[0][1] * fv[ch];
                acc[ch][2] += co[1][0] * fv[ch];
                acc[ch][3] += co[1][1] * fv[ch];
            }
        }

#pragma unroll
    for (int ch = 0; ch < 8; ++ch) {
        int c = chunk * 8 + ch;
        size_t base = (((size_t)(b * 128 + c) * 256 + 2 * y) * 256 + 2 * x);
        float2 o0, o1;
        o0.x = acc[ch][0]; o0.y = acc[ch][1];
        o1.x = acc[ch][2]; o1.y = acc[ch][3];
        *(float2*)(out + base) = o0;
        *(float2*)(out + base + 256) = o1;
    }
}

extern "C" void kernel_launch(void* const* d_in, const int* in_sizes, int n_in,
                              void* d_out, int out_size, void* d_ws, size_t ws_size,
                              hipStream_t stream)
{
    const float* feat  = (const float*)d_in[0];
    const float* guide = (const float*)d_in[1];
    const float* g_w1  = (const float*)d_in[2];
    const float* g_g1  = (const float*)d_in[3];
    const float* g_b1  = (const float*)d_in[4];
    const float* g_w2  = (const float*)d_in[5];
    const float* g_g2  = (const float*)d_in[6];
    const float* g_b2  = (const float*)d_in[7];
    const float* p_w   = (const float*)d_in[8];
    const float* k_w1  = (const float*)d_in[9];
    const float* k_w2  = (const float*)d_in[10];
    const float* k_b2  = (const float*)d_in[11];

    float* out = (float*)d_out;

    // bf16 NHWC intermediates inside d_out (dead before k_out2 writes):
    ushort_t* x1 = (ushort_t*)out;                    // 4,194,304 bf16 = 8.4MB
    ushort_t* x2 = (ushort_t*)(out + 2097152);        // 4,194,304 bf16

    // workspace layout
    float*    kern48 = (float*)d_ws;                  // 1,572,864 f32 (6.3MB)
    ushort_t* fs     = (ushort_t*)((char*)d_ws + 6291456);   // 1,048,576 bf16
    ushort_t* wpk    = (ushort_t*)((char*)d_ws + 8388608);   // 31,744 bf16
    float*    part   = (float*)((char*)d_ws + 8454144);      // 256*64 f32 = 64KB
    float*    ab1    = (float*)((char*)d_ws + 8519680);      // 64 f32
    float*    ab2    = (float*)((char*)d_ws + 8519936);      // 64 f32
    ushort_t* w2pk   = wpk;
    ushort_t* kw1pk  = wpk + 9216;
    ushort_t* pwpk   = wpk + 27648;

    k_phase1<<<636, 256, 0, stream>>>(guide, g_w1, g_w2, k_w1, p_w, x1, wpk);
    k_statsP<<<256, 256, 0, stream>>>(x1, part);
    k_statsF<<<1, 64, 0, stream>>>(part, g_g1, g_b1, ab1);
    k_conv2p<<<768, 256, 0, stream>>>(x1, ab1, w2pk, x2, feat, pwpk, fs);
    k_statsP<<<256, 256, 0, stream>>>(x2, part);
    k_statsF<<<1, 64, 0, stream>>>(part, g_g2, g_b2, ab2);
    k_kern_m<<<512, 256, 0, stream>>>(x2, ab2, fs, kw1pk, k_w2, k_b2, kern48);
    k_out2<<<2048, 256, 0, stream>>>(feat, kern48, out);
}